// Round 10
// baseline (329.241 us; speedup 1.0000x reference)
//
#include <hip/hip_runtime.h>
#include <math.h>

// ---------------- problem constants ----------------
constexpr int B_    = 2;
constexpr int L_    = 2048;
constexpr int NROW  = B_ * L_;     // 4096 rows per branch
constexpr int MROW  = 2 * NROW;    // 8192 merged rows (branch-major)
constexpr int HALF_ = 256;
constexpr int DS_   = 128;

constexpr float LOG2E = 1.4426950408889634f;

// ---------------- ws layout ----------------
// fp32 region (float element offsets)
constexpr size_t OFF_MINP = 0;                                    // 32 (minA partials)
constexpr size_t OFF_BCMX = 32;                                   // 4 (uint atomics: brB,brC x2)
constexpr size_t OFF_XZ   = 64;                                   // 8192x512 (transient)
constexpr size_t OFF_YT   = OFF_XZ + (size_t)MROW * 256;          // alias: 2x256x4096 (after conv)
constexpr size_t OFF_XDBL = OFF_XZ + (size_t)MROW * 512;          // 8192x288
constexpr size_t OFF_XS   = OFF_XDBL + (size_t)MROW * 288;        // 8192x256
constexpr size_t OFF_BS   = OFF_XS  + (size_t)MROW * 256;         // 2 x 4096x128
constexpr size_t OFF_CS   = OFF_BS  + (size_t)2 * NROW * 128;     // 2 x 4096x128
constexpr size_t OFF_DTT  = OFF_CS  + (size_t)2 * NROW * 128;     // 2 x 256x4096
constexpr size_t OFF_DUT  = OFF_DTT + (size_t)2 * 256 * 4096;
constexpr size_t OFF_UDT  = OFF_DUT + (size_t)2 * 256 * 4096;
constexpr size_t FLOAT_END = OFF_UDT + (size_t)2 * 256 * 4096;

// bf16 region (ushort element offsets, based at ws + FLOAT_END floats)
constexpr size_t HOFF_XINH = 0;                                   // 8192x512
constexpr size_t HOFF_XINL = HOFF_XINH + (size_t)MROW * 512;
constexpr size_t HOFF_YZH  = HOFF_XINH;                           // alias (xin dead after in_proj)
constexpr size_t HOFF_YZL  = HOFF_XINL;
constexpr size_t HOFF_XSH  = HOFF_XINL + (size_t)MROW * 512;      // 8192x256
constexpr size_t HOFF_XSL  = HOFF_XSH  + (size_t)MROW * 256;
constexpr size_t HOFF_INWH = HOFF_XSL  + (size_t)MROW * 256;      // 2 x 512x512
constexpr size_t HOFF_INWL = HOFF_INWH + 524288;
constexpr size_t HOFF_XWH  = HOFF_INWL + 524288;                  // 2 x 288x256
constexpr size_t HOFF_XWL  = HOFF_XWH  + 147456;
constexpr size_t HOFF_OUTWH= HOFF_XWL  + 147456;                  // 2 x 512x512
constexpr size_t HOFF_OUTWL= HOFF_OUTWH+ 524288;

constexpr size_t WST_IN = 262144;   // per-branch in/out weight elems
constexpr size_t WST_X  = 73728;    // per-branch x_proj weight elems

// pre_all block ranges
constexpr int PRE_MINA = 32;
constexpr int PRE_WSPL = (1196032 + 255) / 256;   // 4672
constexpr int PRE_TIN  = 64 * 16 * 4;             // 4096
constexpr int PRE_BLOCKS = PRE_MINA + PRE_WSPL + PRE_TIN;

// ---------------- types / helpers ----------------
typedef __bf16 bf16x8 __attribute__((ext_vector_type(8)));
typedef float  f32x4  __attribute__((ext_vector_type(4)));

__device__ __forceinline__ unsigned short bf16rn(float x) {
    unsigned u = __float_as_uint(x);
    unsigned r = (u + 0x7FFFu + ((u >> 16) & 1u)) >> 16;
    return (unsigned short)r;
}
__device__ __forceinline__ void split2(float x, unsigned short& h, unsigned short& l) {
    h = bf16rn(x);
    float hf = __uint_as_float(((unsigned)h) << 16);
    l = bf16rn(x - hf);
}

__device__ __forceinline__ float shrinkf(float v, float thr) {
    float a = fabsf(v) - thr;
    a = fmaxf(a, 0.0f);
    float r = copysignf(a, v);
    return (v == 0.0f) ? 0.0f : r;
}
__device__ __forceinline__ float siluf(float v) { return v / (1.0f + __expf(-v)); }
__device__ __forceinline__ float softplusf(float v) {
    return fmaxf(v, 0.0f) + log1pf(__expf(-fabsf(v)));
}
__device__ __forceinline__ float rlanef(float v, int l) {
    return __int_as_float(__builtin_amdgcn_readlane(__float_as_int(v), l));
}
// monotone float<->uint key for atomicMax on signed floats
__device__ __forceinline__ unsigned fkey(float f) {
    unsigned u = __float_as_uint(f);
    return (u >> 31) ? ~u : (u | 0x80000000u);
}
__device__ __forceinline__ float funkey(unsigned k) {
    unsigned u = (k >> 31) ? (k & 0x7FFFFFFFu) : ~k;
    return __uint_as_float(u);
}

// ---------------- pre_all: minA + weight splits + input transpose, one dispatch ----------------
__global__ __launch_bounds__(256) void pre_all(const float* __restrict__ A_log,
                                               const float* __restrict__ inp,
                                               const float* __restrict__ in_w0,
                                               const float* __restrict__ in_w1,
                                               const float* __restrict__ outw0,
                                               const float* __restrict__ outw1,
                                               const float* __restrict__ xw0,
                                               const float* __restrict__ xw1,
                                               float* __restrict__ ws,
                                               unsigned* __restrict__ bcmax,
                                               unsigned short* __restrict__ hb) {
    int bid = blockIdx.x;
    int tid = threadIdx.x;
    if (bid < PRE_MINA) {
        __shared__ float sbuf[8];
        int i = bid * 1024 + tid * 4;
        float4 v = *(const float4*)(A_log + i);
        float mv = fminf(fminf(v.x, v.y), fminf(v.z, v.w));
        #pragma unroll
        for (int off = 32; off > 0; off >>= 1) mv = fminf(mv, __shfl_xor(mv, off));
        if ((tid & 63) == 0) sbuf[tid >> 6] = mv;
        __syncthreads();
        if (tid == 0) {
            float r = fminf(fminf(sbuf[0], sbuf[1]), fminf(sbuf[2], sbuf[3]));
            ws[OFF_MINP + bid] = r;
        }
        if (bid == 0 && tid < 4) bcmax[tid] = 0u;
    } else if (bid < PRE_MINA + PRE_WSPL) {
        int i = (bid - PRE_MINA) * 256 + tid;
        if (i >= 1196032) return;
        const float* src;
        size_t hbase, lbase;
        int off;
        if (i < 1048576) {
            int t = i >> 18;
            off = i & 262143;
            src = (t == 0) ? in_w0 : (t == 1) ? in_w1 : (t == 2) ? outw0 : outw1;
            if (t < 2) { hbase = HOFF_INWH + (size_t)t * WST_IN;  lbase = HOFF_INWL + (size_t)t * WST_IN; }
            else       { hbase = HOFF_OUTWH + (size_t)(t - 2) * WST_IN; lbase = HOFF_OUTWL + (size_t)(t - 2) * WST_IN; }
        } else {
            int j = i - 1048576;
            int t = (j < (int)WST_X) ? 0 : 1;
            off = j - t * (int)WST_X;
            src = t ? xw1 : xw0;
            hbase = HOFF_XWH + (size_t)t * WST_X;
            lbase = HOFF_XWL + (size_t)t * WST_X;
        }
        unsigned short h, l;
        split2(src[off], h, l);
        hb[hbase + off] = h;
        hb[lbase + off] = l;
    } else {
        __shared__ float tile[32][33];
        int idx = bid - PRE_MINA - PRE_WSPL;    // 0..4095
        int bx = idx & 63;          // t block (64)
        int by = (idx >> 6) & 15;   // ch block (16)
        int z  = idx >> 10;         // 0..3
        int br = z >> 1;
        int b  = z & 1;
        int t0 = bx * 32;
        int m0 = by * 32;
        int tx = tid & 31;
        int ty = tid >> 5;
        #pragma unroll
        for (int k = 0; k < 4; k++) {
            tile[ty + 8 * k][tx] =
                inp[((size_t)b * 1024 + br * 512 + m0 + ty + 8 * k) * L_ + t0 + tx];
        }
        __syncthreads();
        #pragma unroll
        for (int k = 0; k < 4; k++) {
            size_t dst = ((size_t)br * NROW + (size_t)b * L_ + t0 + ty + 8 * k) * 512 + m0 + tx;
            unsigned short h, l;
            split2(tile[tx][ty + 8 * k], h, l);
            hb[HOFF_XINH + dst] = h;
            hb[HOFF_XINL + dst] = l;
        }
    }
}

// ---------------- MFMA GEMM (bf16x3) with register prefetch ----------------
template <int NGUARD, int DOMAX>
__global__ __launch_bounds__(256) void gemm_mfma(const unsigned short* __restrict__ Ah,
                                                 const unsigned short* __restrict__ Al, int lda,
                                                 const unsigned short* __restrict__ WhB,
                                                 const unsigned short* __restrict__ WlB,
                                                 size_t wstride,
                                                 float* __restrict__ C, int ldc,
                                                 int N, int K,
                                                 unsigned* __restrict__ bcmax) {
    __shared__ __align__(16) unsigned short sAh[128 * 40];
    __shared__ __align__(16) unsigned short sAl[128 * 40];
    __shared__ __align__(16) unsigned short sBh[64 * 40];
    __shared__ __align__(16) unsigned short sBl[64 * 40];
    int tid  = threadIdx.x;
    int wid  = tid >> 6;
    int lane = tid & 63;
    int fr   = lane & 15;
    int kg   = lane >> 4;
    int mblk = blockIdx.y * 128;
    int nblk = blockIdx.x * 64;
    int br   = (mblk >= NROW) ? 1 : 0;
    const unsigned short* Wh = WhB + (size_t)br * wstride;
    const unsigned short* Wl = WlB + (size_t)br * wstride;
    int srow = tid >> 2;
    int skp  = (tid & 3) * 8;
    bool brow_ok = (!NGUARD) || ((nblk + srow) < N);

    const unsigned short* pA0 = Ah + (size_t)(mblk + srow) * lda + skp;
    const unsigned short* pA1 = Ah + (size_t)(mblk + 64 + srow) * lda + skp;
    const unsigned short* pL0 = Al + (size_t)(mblk + srow) * lda + skp;
    const unsigned short* pL1 = Al + (size_t)(mblk + 64 + srow) * lda + skp;
    const unsigned short* pBh = Wh + (size_t)(nblk + srow) * K + skp;
    const unsigned short* pBl = Wl + (size_t)(nblk + srow) * K + skp;

    f32x4 acc[2][4] = {};

    uint4 rah0 = *(const uint4*)(pA0);
    uint4 rah1 = *(const uint4*)(pA1);
    uint4 ral0 = *(const uint4*)(pL0);
    uint4 ral1 = *(const uint4*)(pL1);
    uint4 rbh = {0, 0, 0, 0}, rbl = {0, 0, 0, 0};
    if (brow_ok) {
        rbh = *(const uint4*)(pBh);
        rbl = *(const uint4*)(pBl);
    }

    for (int k0 = 0; k0 < K; k0 += 32) {
        __syncthreads();
        *(uint4*)(sAh + srow * 40 + skp) = rah0;
        *(uint4*)(sAh + (64 + srow) * 40 + skp) = rah1;
        *(uint4*)(sAl + srow * 40 + skp) = ral0;
        *(uint4*)(sAl + (64 + srow) * 40 + skp) = ral1;
        *(uint4*)(sBh + srow * 40 + skp) = rbh;
        *(uint4*)(sBl + srow * 40 + skp) = rbl;
        __syncthreads();

        int kn = k0 + 32;
        if (kn < K) {
            rah0 = *(const uint4*)(pA0 + kn);
            rah1 = *(const uint4*)(pA1 + kn);
            ral0 = *(const uint4*)(pL0 + kn);
            ral1 = *(const uint4*)(pL1 + kn);
            if (brow_ok) {
                rbh = *(const uint4*)(pBh + kn);
                rbl = *(const uint4*)(pBl + kn);
            }
        }

        bf16x8 ah0 = *(const bf16x8*)(sAh + (wid * 32 + fr) * 40 + kg * 8);
        bf16x8 ah1 = *(const bf16x8*)(sAh + (wid * 32 + 16 + fr) * 40 + kg * 8);
        bf16x8 al0 = *(const bf16x8*)(sAl + (wid * 32 + fr) * 40 + kg * 8);
        bf16x8 al1 = *(const bf16x8*)(sAl + (wid * 32 + 16 + fr) * 40 + kg * 8);
        #pragma unroll
        for (int nt = 0; nt < 4; nt++) {
            bf16x8 bh = *(const bf16x8*)(sBh + (nt * 16 + fr) * 40 + kg * 8);
            bf16x8 bl = *(const bf16x8*)(sBl + (nt * 16 + fr) * 40 + kg * 8);
            acc[0][nt] = __builtin_amdgcn_mfma_f32_16x16x32_bf16(ah0, bh, acc[0][nt], 0, 0, 0);
            acc[0][nt] = __builtin_amdgcn_mfma_f32_16x16x32_bf16(ah0, bl, acc[0][nt], 0, 0, 0);
            acc[0][nt] = __builtin_amdgcn_mfma_f32_16x16x32_bf16(al0, bh, acc[0][nt], 0, 0, 0);
            acc[1][nt] = __builtin_amdgcn_mfma_f32_16x16x32_bf16(ah1, bh, acc[1][nt], 0, 0, 0);
            acc[1][nt] = __builtin_amdgcn_mfma_f32_16x16x32_bf16(ah1, bl, acc[1][nt], 0, 0, 0);
            acc[1][nt] = __builtin_amdgcn_mfma_f32_16x16x32_bf16(al1, bh, acc[1][nt], 0, 0, 0);
        }
    }
    #pragma unroll
    for (int mt = 0; mt < 2; mt++) {
        #pragma unroll
        for (int nt = 0; nt < 4; nt++) {
            int col = nblk + nt * 16 + fr;
            if (NGUARD && col >= N) continue;
            #pragma unroll
            for (int r = 0; r < 4; r++) {
                int row = mblk + wid * 32 + mt * 16 + kg * 4 + r;
                C[(size_t)row * ldc + col] = acc[mt][nt][r];
            }
        }
    }
    if (DOMAX) {
        float mb = -INFINITY, mc = -INFINITY;
        #pragma unroll
        for (int nt = 0; nt < 4; nt++) {
            int c16 = nblk + nt * 16;
            if (c16 >= 32 && c16 < 160) {
                #pragma unroll
                for (int mt = 0; mt < 2; mt++)
                    #pragma unroll
                    for (int r = 0; r < 4; r++) mb = fmaxf(mb, acc[mt][nt][r]);
            } else if (c16 >= 160 && c16 < 288) {
                #pragma unroll
                for (int mt = 0; mt < 2; mt++)
                    #pragma unroll
                    for (int r = 0; r < 4; r++) mc = fmaxf(mc, acc[mt][nt][r]);
            }
        }
        #pragma unroll
        for (int off = 32; off > 0; off >>= 1) {
            mb = fmaxf(mb, __shfl_xor(mb, off));
            mc = fmaxf(mc, __shfl_xor(mc, off));
        }
        if (lane == 0) {
            if (mb > -INFINITY) atomicMax(bcmax + 2 * br,     fkey(mb));
            if (mc > -INFINITY) atomicMax(bcmax + 2 * br + 1, fkey(mc));
        }
    }
}

// ---------------- depthwise conv (k=4) + SiLU, vectorized 4 channels/thread ----------------
__global__ __launch_bounds__(256) void conv_silu_kernel(const float* __restrict__ xz,
                                                        float* __restrict__ xs,
                                                        unsigned short* __restrict__ xsh,
                                                        unsigned short* __restrict__ xsl,
                                                        unsigned short* __restrict__ yzh,
                                                        unsigned short* __restrict__ yzl,
                                                        const float* __restrict__ wx0,
                                                        const float* __restrict__ wx1,
                                                        const float* __restrict__ wz0,
                                                        const float* __restrict__ wz1) {
    int gid = blockIdx.x * 256 + threadIdx.x;   // over MROW*64
    int c4  = (gid & 63) << 2;
    int row = gid >> 6;
    int br  = row >> 12;
    int t   = row & (L_ - 1);
    const float* wx = br ? wx1 : wx0;
    const float* wz = br ? wz1 : wz0;
    float4 wxv[4], wzv[4];
    #pragma unroll
    for (int k = 0; k < 4; k++) {
        wxv[k] = *(const float4*)(wx + (c4 + k) * 4);
        wzv[k] = *(const float4*)(wz + (c4 + k) * 4);
    }
    float4 ax = {0, 0, 0, 0}, az = {0, 0, 0, 0};
    #pragma unroll
    for (int j = 0; j < 4; j++) {
        int tt = t + j - 1;
        if (tt >= 0 && tt < L_) {
            const float* p = xz + (size_t)(row + j - 1) * 512;
            float4 vx = *(const float4*)(p + c4);
            float4 vz = *(const float4*)(p + 256 + c4);
            ax.x = fmaf(vx.x, ((const float*)&wxv[0])[j], ax.x);
            ax.y = fmaf(vx.y, ((const float*)&wxv[1])[j], ax.y);
            ax.z = fmaf(vx.z, ((const float*)&wxv[2])[j], ax.z);
            ax.w = fmaf(vx.w, ((const float*)&wxv[3])[j], ax.w);
            az.x = fmaf(vz.x, ((const float*)&wzv[0])[j], az.x);
            az.y = fmaf(vz.y, ((const float*)&wzv[1])[j], az.y);
            az.z = fmaf(vz.z, ((const float*)&wzv[2])[j], az.z);
            az.w = fmaf(vz.w, ((const float*)&wzv[3])[j], az.w);
        }
    }
    float4 sx, sz;
    sx.x = siluf(ax.x); sx.y = siluf(ax.y); sx.z = siluf(ax.z); sx.w = siluf(ax.w);
    sz.x = siluf(az.x); sz.y = siluf(az.y); sz.z = siluf(az.z); sz.w = siluf(az.w);
    *(float4*)(xs + (size_t)row * 256 + c4) = sx;
    ushort4 hx, lx, hz, lz;
    split2(sx.x, hx.x, lx.x); split2(sx.y, hx.y, lx.y);
    split2(sx.z, hx.z, lx.z); split2(sx.w, hx.w, lx.w);
    split2(sz.x, hz.x, lz.x); split2(sz.y, hz.y, lz.y);
    split2(sz.z, hz.z, lz.z); split2(sz.w, hz.w, lz.w);
    *(ushort4*)(xsh + (size_t)row * 256 + c4) = hx;
    *(ushort4*)(xsl + (size_t)row * 256 + c4) = lx;
    *(ushort4*)(yzh + (size_t)row * 512 + 256 + c4) = hz;
    *(ushort4*)(yzl + (size_t)row * 512 + 256 + c4) = lz;
}

// ---------------- fused dt_proj(K=32)+softplus+prep + shrinkpack ----------------
__global__ __launch_bounds__(256) void dtprep_shrink(const float* __restrict__ A, int lda,
                                                     const float* __restrict__ W0,
                                                     const float* __restrict__ W1,
                                                     const float* __restrict__ b0,
                                                     const float* __restrict__ b1,
                                                     const float* __restrict__ xs,
                                                     const float* __restrict__ Dvec,
                                                     float* __restrict__ dtT,
                                                     float* __restrict__ duT,
                                                     float* __restrict__ udT,
                                                     const unsigned* __restrict__ bcmax,
                                                     float* __restrict__ Bs,
                                                     float* __restrict__ Cs) {
    __shared__ float As[16][68];
    __shared__ float Ws[16][68];
    __shared__ float tb[64 * 68];
    int tid = threadIdx.x;
    int kk = tid & 15;
    int rr = tid >> 4;
    int mblk = blockIdx.y * 64;
    int nblk = blockIdx.x * 64;
    int br = (mblk >= NROW) ? 1 : 0;
    const float* W    = br ? W1 : W0;
    const float* bias = br ? b1 : b0;
    float acc[4][4] = {};
    for (int k0 = 0; k0 < 32; k0 += 16) {
        #pragma unroll
        for (int j = 0; j < 4; j++) {
            As[kk][rr + 16 * j] = A[(size_t)(mblk + rr + 16 * j) * lda + k0 + kk];
        }
        #pragma unroll
        for (int j = 0; j < 4; j++) {
            Ws[kk][rr + 16 * j] = W[(size_t)(nblk + rr + 16 * j) * 32 + k0 + kk];
        }
        __syncthreads();
        int ty = tid >> 4;
        int tx = tid & 15;
        #pragma unroll
        for (int kq = 0; kq < 16; kq++) {
            float a0 = As[kq][ty * 4 + 0];
            float a1 = As[kq][ty * 4 + 1];
            float a2 = As[kq][ty * 4 + 2];
            float a3 = As[kq][ty * 4 + 3];
            float v0 = Ws[kq][tx * 4 + 0];
            float v1 = Ws[kq][tx * 4 + 1];
            float v2 = Ws[kq][tx * 4 + 2];
            float v3 = Ws[kq][tx * 4 + 3];
            acc[0][0] = fmaf(a0, v0, acc[0][0]); acc[0][1] = fmaf(a0, v1, acc[0][1]);
            acc[0][2] = fmaf(a0, v2, acc[0][2]); acc[0][3] = fmaf(a0, v3, acc[0][3]);
            acc[1][0] = fmaf(a1, v0, acc[1][0]); acc[1][1] = fmaf(a1, v1, acc[1][1]);
            acc[1][2] = fmaf(a1, v2, acc[1][2]); acc[1][3] = fmaf(a1, v3, acc[1][3]);
            acc[2][0] = fmaf(a2, v0, acc[2][0]); acc[2][1] = fmaf(a2, v1, acc[2][1]);
            acc[2][2] = fmaf(a2, v2, acc[2][2]); acc[2][3] = fmaf(a2, v3, acc[2][3]);
            acc[3][0] = fmaf(a3, v0, acc[3][0]); acc[3][1] = fmaf(a3, v1, acc[3][1]);
            acc[3][2] = fmaf(a3, v2, acc[3][2]); acc[3][3] = fmaf(a3, v3, acc[3][3]);
        }
        __syncthreads();
    }
    int ty = tid >> 4;
    int tx = tid & 15;
    float dlt[4][4], uu[4][4];
    #pragma unroll
    for (int i = 0; i < 4; i++) {
        int m = mblk + ty * 4 + i;
        #pragma unroll
        for (int j = 0; j < 4; j++) {
            int n = nblk + tx * 4 + j;
            dlt[i][j] = softplusf(acc[i][j] + bias[n]);
            uu[i][j]  = xs[(size_t)m * 256 + n];
        }
    }
    float Dv[4];
    #pragma unroll
    for (int j = 0; j < 4; j++) Dv[j] = Dvec[nblk + tx * 4 + j];

    int mlocbase = mblk & (NROW - 1);
    int nrd  = tid >> 2;
    int mc   = (tid & 3) * 4;
    size_t obase = ((size_t)br * 256 + nblk + nrd) * 4096 + mlocbase;
    #pragma unroll
    for (int pass = 0; pass < 3; pass++) {
        __syncthreads();
        #pragma unroll
        for (int i = 0; i < 4; i++) {
            #pragma unroll
            for (int j = 0; j < 4; j++) {
                float v = (pass == 0) ? dlt[i][j] * LOG2E
                        : (pass == 1) ? dlt[i][j] * uu[i][j]
                                      : uu[i][j] * Dv[j];
                tb[(tx * 4 + j) * 68 + ty * 4 + i] = v;
            }
        }
        __syncthreads();
        float* dst = (pass == 0) ? dtT : (pass == 1) ? duT : udT;
        #pragma unroll
        for (int it = 0; it < 4; it++) {
            int cc = mc + it * 16;
            float4 v = *(const float4*)(tb + nrd * 68 + cc);
            *(float4*)(dst + obase + cc) = v;
        }
    }
    {
        int q = blockIdx.x;
        int isC = q >> 1;
        int cbase = (q & 1) * 64;
        int xoff = isC ? (160 + cbase) : (32 + cbase);
        float thr = 0.1f * funkey(bcmax[2 * br + isC]);
        float* dstArr = isC ? Cs : Bs;
        int r = tid >> 2;
        int c0 = (tid & 3) * 16;
        const float* src = A + (size_t)(mblk + r) * lda + xoff + c0;
        float* dp = dstArr + (size_t)(mblk + r) * 128 + cbase + c0;
        #pragma unroll
        for (int i = 0; i < 16; i += 4) {
            float4 v = *(const float4*)(src + i);
            float4 o;
            o.x = shrinkf(v.x, thr);
            o.y = shrinkf(v.y, thr);
            o.z = shrinkf(v.z, thr);
            o.w = shrinkf(v.w, thr);
            *(float4*)(dp + i) = o;
        }
    }
}

// ---------------- selective scan v4: 4-deep B/C register pipeline ----------------
// 2 waves (128 thr) per chain, 1 state/lane. B/C prefetched 4 batches (32 t)
// ahead (~960 cyc) to cover HBM/L3 miss latency; buffer idx compile-time (m&3).
// LDS-limited occupancy (4 blocks/CU) -> the +64 VGPRs are free.
__global__ __launch_bounds__(128) void scan3_kernel(float* __restrict__ ws,
                                                    const float* __restrict__ A_log,
                                                    const float* __restrict__ eps) {
    int blk  = blockIdx.x;
    int xcd  = blk & 7;
    int slot = blk >> 3;
    int combo = xcd >> 1;
    int d  = (xcd & 1) * 128 + slot;
    int br = combo >> 1;
    int b  = combo & 1;
    int tid = threadIdx.x;
    int lt  = tid & 63;

    float pv = ws[OFF_MINP + (tid & 31)];
    #pragma unroll
    for (int off = 16; off > 0; off >>= 1) pv = fminf(pv, __shfl_xor(pv, off));
    float e  = 1.0f + eps[0];
    float m1 = -e * __expf(pv);
    float t1 = 0.1f * m1;
    float t2 = 0.1f * shrinkf(m1, t1);
    float base = -e * __expf(A_log[d * 128 + tid]);
    float a = shrinkf(base, t1);
    if (br) a = shrinkf(a, t2);

    size_t dchain = ((size_t)br * 256 + d) * 4096 + (size_t)b * L_;
    const float* dtT = ws + OFF_DTT + dchain;
    const float* duT = ws + OFF_DUT + dchain;
    const float* udT = ws + OFF_UDT + dchain;
    const float* Bp  = ws + OFF_BS + ((size_t)br * NROW + (size_t)b * L_) * 128 + tid;
    const float* Cp  = ws + OFF_CS + ((size_t)br * NROW + (size_t)b * L_) * 128 + tid;
    float*       yTp = ws + OFF_YT + dchain;

    __shared__ float red[64 * 132];
    __shared__ float comb[64];

    float h = 0.0f;

    float Bb[4][8], Cb[4][8];
    float dt_c = dtT[lt];
    float du_c = duT[lt];
    float ud_c = udT[lt];
    float dt_n = 0.f, du_n = 0.f, ud_n = 0.f;
    #pragma unroll
    for (int q = 0; q < 4; q++) {
        #pragma unroll
        for (int j = 0; j < 8; j++) {
            Bb[q][j] = Bp[((size_t)q * 8 + j) * 128];
            Cb[q][j] = Cp[((size_t)q * 8 + j) * 128];
        }
    }

    for (int c = 0; c < 32; c++) {
        if (c < 31) {
            dt_n = dtT[(c + 1) * 64 + lt];
            du_n = duT[(c + 1) * 64 + lt];
            ud_n = udT[(c + 1) * 64 + lt];
        }
        #pragma unroll
        for (int m = 0; m < 8; m++) {
            const int cur = m & 3;     // (c*8+m)&3 == m&3 (c*8 ≡ 0 mod 4)
            #pragma unroll
            for (int j = 0; j < 8; j++) {
                const int tl = m * 8 + j;
                float dt2 = rlanef(dt_c, tl);
                float du  = rlanef(du_c, tl);
                float ev = __builtin_amdgcn_exp2f(dt2 * a);
                h = fmaf(ev, h, du * Bb[cur][j]);
                red[tl * 132 + tid] = h * Cb[cur][j];
            }
            int nb = c * 8 + m + 4;    // refill 4 batches (32 t) ahead
            if (nb < 256) {
                #pragma unroll
                for (int j = 0; j < 8; j++) {
                    Bb[cur][j] = Bp[((size_t)nb * 8 + j) * 128];
                    Cb[cur][j] = Cp[((size_t)nb * 8 + j) * 128];
                }
            }
        }
        __syncthreads();
        {
            const float* rp = &red[(tid & 63) * 132 + (tid >> 6) * 64];
            float s0 = 0.f, s1 = 0.f, s2 = 0.f, s3 = 0.f;
            #pragma unroll
            for (int i = 0; i < 64; i += 4) {
                float4 v = *(const float4*)(rp + i);
                s0 += v.x; s1 += v.y; s2 += v.z; s3 += v.w;
            }
            float part = (s0 + s1) + (s2 + s3);
            if (tid >= 64) comb[tid - 64] = part;
            __syncthreads();
            if (tid < 64) yTp[c * 64 + tid] = part + comb[tid] + ud_c;
        }
        __syncthreads();
        dt_c = dt_n;
        du_c = du_n;
        ud_c = ud_n;
    }
}

// ---------------- yT -> yz bf16 split (y half), merged: grid (8, 128, 2) ----------------
__global__ __launch_bounds__(256) void transpose_yz_kernel(const float* __restrict__ yT,
                                                           unsigned short* __restrict__ yzh,
                                                           unsigned short* __restrict__ yzl) {
    __shared__ float tile[32][33];
    int br = blockIdx.z;
    int m0 = blockIdx.x * 32;
    int n0 = blockIdx.y * 32;
    int tx = threadIdx.x;
    int ty = threadIdx.y;
    #pragma unroll
    for (int k = 0; k < 4; k++) {
        tile[ty + 8 * k][tx] = yT[((size_t)br * 256 + m0 + ty + 8 * k) * 4096 + n0 + tx];
    }
    __syncthreads();
    #pragma unroll
    for (int k = 0; k < 4; k++) {
        size_t dst = ((size_t)br * NROW + n0 + ty + 8 * k) * 512 + m0 + tx;
        unsigned short h, l;
        split2(tile[tx][ty + 8 * k], h, l);
        yzh[dst] = h; yzl[dst] = l;
    }
}

// ---------------- host-side launch ----------------
extern "C" void kernel_launch(void* const* d_in, const int* in_sizes, int n_in,
                              void* d_out, int out_size, void* d_ws, size_t ws_size,
                              hipStream_t stream) {
    const float* inp   = (const float*)d_in[0];
    const float* in_w[2]  = {(const float*)d_in[1],  (const float*)d_in[8]};
    const float* cxw[2]   = {(const float*)d_in[2],  (const float*)d_in[9]};
    const float* czw[2]   = {(const float*)d_in[3],  (const float*)d_in[10]};
    const float* xw[2]    = {(const float*)d_in[4],  (const float*)d_in[11]};
    const float* dtw[2]   = {(const float*)d_in[5],  (const float*)d_in[12]};
    const float* dtb[2]   = {(const float*)d_in[6],  (const float*)d_in[13]};
    const float* outw[2]  = {(const float*)d_in[7],  (const float*)d_in[14]};
    const float* A_log = (const float*)d_in[15];
    const float* Dvec  = (const float*)d_in[16];
    const float* eps   = (const float*)d_in[17];
    float* out = (float*)d_out;
    float* ws  = (float*)d_ws;
    unsigned short* hb = (unsigned short*)(ws + FLOAT_END);
    unsigned* bcmax = (unsigned*)(ws + OFF_BCMX);

    pre_all<<<PRE_BLOCKS, 256, 0, stream>>>(
        A_log, inp, in_w[0], in_w[1], outw[0], outw[1], xw[0], xw[1],
        ws, bcmax, hb);

    gemm_mfma<0, 0><<<dim3(512 / 64, MROW / 128), 256, 0, stream>>>(
        hb + HOFF_XINH, hb + HOFF_XINL, 512,
        hb + HOFF_INWH, hb + HOFF_INWL, WST_IN,
        ws + OFF_XZ, 512, 512, 512, nullptr);

    conv_silu_kernel<<<(MROW * 64) / 256, 256, 0, stream>>>(
        ws + OFF_XZ, ws + OFF_XS, hb + HOFF_XSH, hb + HOFF_XSL,
        hb + HOFF_YZH, hb + HOFF_YZL, cxw[0], cxw[1], czw[0], czw[1]);

    gemm_mfma<1, 1><<<dim3((288 + 63) / 64, MROW / 128), 256, 0, stream>>>(
        hb + HOFF_XSH, hb + HOFF_XSL, 256,
        hb + HOFF_XWH, hb + HOFF_XWL, WST_X,
        ws + OFF_XDBL, 288, 288, 256, bcmax);

    dtprep_shrink<<<dim3(4, MROW / 64), 256, 0, stream>>>(
        ws + OFF_XDBL, 288, dtw[0], dtw[1], dtb[0], dtb[1],
        ws + OFF_XS, Dvec,
        ws + OFF_DTT, ws + OFF_DUT, ws + OFF_UDT,
        bcmax, ws + OFF_BS, ws + OFF_CS);

    scan3_kernel<<<dim3(1024), 128, 0, stream>>>(ws, A_log, eps);

    transpose_yz_kernel<<<dim3(256 / 32, NROW / 32, 2), dim3(32, 8), 0, stream>>>(
        ws + OFF_YT, hb + HOFF_YZH, hb + HOFF_YZL);

    gemm_mfma<0, 0><<<dim3(512 / 64, MROW / 128), 256, 0, stream>>>(
        hb + HOFF_YZH, hb + HOFF_YZL, 512,
        hb + HOFF_OUTWH, hb + HOFF_OUTWL, WST_IN,
        out, 512, 512, 512, nullptr);
}